// Round 1
// baseline (602.526 us; speedup 1.0000x reference)
//
#include <hip/hip_runtime.h>
#include <hip/hip_bf16.h>
#include <cmath>

#define NT 4096      // B*S tokens
#define HD 768
#define ID 3072
#define NE 7
#define NP 8192      // NT * TOP_K
#define TM 128
#define TN 128
#define BK 32
#define LDA 40       // padded LDS row (bf16 elems): 80B stride -> 2-way bank alias (free)

using short8 = __attribute__((ext_vector_type(8))) short;
using f32x4  = __attribute__((ext_vector_type(4))) float;
typedef __hip_bfloat16 bf16;

// ---------------- gating: logits, top-2 softmax, routing lists, x->bf16 ----------------
__global__ __launch_bounds__(64) void gate_kernel(
    const float* __restrict__ x, const float* __restrict__ wg, const float* __restrict__ bg,
    float* __restrict__ gate_out, bf16* __restrict__ xb,
    float* __restrict__ pair_w, int* __restrict__ elist, int* __restrict__ counts)
{
  int t = blockIdx.x;
  int lane = threadIdx.x;
  const float* xr = x + (size_t)t * HD;
  float acc[NE];
#pragma unroll
  for (int e = 0; e < NE; e++) acc[e] = 0.f;
#pragma unroll
  for (int j = 0; j < HD / 64; j++) {
    int h = lane + j * 64;
    float xv = xr[h];
    xb[(size_t)t * HD + h] = __float2bfloat16(xv);
    const float* wr = wg + (size_t)h * NE;
#pragma unroll
    for (int e = 0; e < NE; e++) acc[e] += xv * wr[e];
  }
#pragma unroll
  for (int e = 0; e < NE; e++) {
    float v = acc[e];
    for (int s = 32; s > 0; s >>= 1) v += __shfl_down(v, s, 64);
    acc[e] = v;
  }
  if (lane == 0) {
    float lg[NE];
#pragma unroll
    for (int e = 0; e < NE; e++) lg[e] = acc[e] + bg[e];
    int i0 = 0;
    for (int e = 1; e < NE; e++) if (lg[e] > lg[i0]) i0 = e;  // first index wins ties (matches top_k)
    int i1 = -1;
    for (int e = 0; e < NE; e++) {
      if (e == i0) continue;
      if (i1 < 0 || lg[e] > lg[i1]) i1 = e;
    }
    float v0 = lg[i0], v1 = lg[i1];
    float e1 = expf(v1 - v0);
    float inv = 1.f / (1.f + e1);
    float w0 = inv, w1v = e1 * inv;
    float* go = gate_out + (size_t)t * NE;
#pragma unroll
    for (int e = 0; e < NE; e++) go[e] = 0.f;
    go[i0] = w0; go[i1] = w1v;
    pair_w[2 * t + 0] = w0;
    pair_w[2 * t + 1] = w1v;
    int p0 = atomicAdd(&counts[i0], 1);
    elist[i0 * NP + p0] = 2 * t;
    int p1 = atomicAdd(&counts[i1], 1);
    elist[i1 * NP + p1] = 2 * t + 1;
  }
}

// ---------------- fp32 [E][K][N] -> bf16 [E][N][K] transpose ----------------
__global__ __launch_bounds__(256) void transpose_cvt_kernel(
    const float* __restrict__ src, bf16* __restrict__ dst, int K, int N)
{
  __shared__ float tile[32][33];
  int e = blockIdx.z;
  int n0 = blockIdx.x * 32;
  int k0 = blockIdx.y * 32;
  const float* s = src + (size_t)e * K * N;
  bf16* d = dst + (size_t)e * K * N;
  int tx = threadIdx.x & 31;
  int ty = threadIdx.x >> 5;  // 0..7
#pragma unroll
  for (int i = 0; i < 4; i++)
    tile[ty + i * 8][tx] = s[(size_t)(k0 + ty + i * 8) * N + n0 + tx];
  __syncthreads();
#pragma unroll
  for (int i = 0; i < 4; i++)
    d[(size_t)(n0 + ty + i * 8) * K + k0 + tx] = __float2bfloat16(tile[tx][ty + i * 8]);
}

// ---------------- grouped GEMM 1: h = gelu(x_g @ W1e + b1e), bf16 out ----------------
__global__ __launch_bounds__(256) void ffn1_kernel(
    const bf16* __restrict__ xb, const bf16* __restrict__ w1t, const float* __restrict__ b1,
    const int* __restrict__ counts, const int* __restrict__ elist, bf16* __restrict__ hbuf)
{
  __shared__ bf16 As[TM][LDA];
  __shared__ bf16 Bs[TN][LDA];
  __shared__ int plist[TM];

  int tid = threadIdx.x;
  int e, base = 0, cnt = 0, acct = 0;
  bool found = false;
  for (e = 0; e < NE; e++) {
    cnt = counts[e];
    int tiles = (cnt + TM - 1) / TM;
    if ((int)blockIdx.x < acct + tiles) { base = ((int)blockIdx.x - acct) * TM; found = true; break; }
    acct += tiles;
  }
  if (!found) return;

  if (tid < TM) {
    int r = base + tid;
    plist[tid] = (r < cnt) ? elist[e * NP + r] : -1;
  }
  __syncthreads();

  const int n0 = blockIdx.y * TN;
  const bf16* Bsrc = w1t + (size_t)e * ID * HD;  // [ID][HD] bf16, K-contiguous

  int wave = tid >> 6, lane = tid & 63;
  int wm = (wave & 1) << 6, wn = (wave >> 1) << 6;
  int lr = lane & 15, quad = lane >> 4;

  f32x4 acc[4][4] = {};

  for (int k0 = 0; k0 < HD; k0 += BK) {
#pragma unroll
    for (int c = tid; c < 512; c += 256) {
      int row = c >> 2, co = (c & 3) << 3;
      int p = plist[row];
      short8 v = {};
      if (p >= 0) v = *(const short8*)(xb + (size_t)(p >> 1) * HD + k0 + co);
      *(short8*)&As[row][co] = v;
    }
#pragma unroll
    for (int c = tid; c < 512; c += 256) {
      int row = c >> 2, co = (c & 3) << 3;
      *(short8*)&Bs[row][co] = *(const short8*)(Bsrc + (size_t)(n0 + row) * HD + k0 + co);
    }
    __syncthreads();
    short8 af[4], bfr[4];
#pragma unroll
    for (int i = 0; i < 4; i++) af[i] = *(const short8*)&As[wm + i * 16 + lr][quad * 8];
#pragma unroll
    for (int j = 0; j < 4; j++) bfr[j] = *(const short8*)&Bs[wn + j * 16 + lr][quad * 8];
#pragma unroll
    for (int i = 0; i < 4; i++)
#pragma unroll
      for (int j = 0; j < 4; j++)
        acc[i][j] = __builtin_amdgcn_mfma_f32_16x16x32_bf16(af[i], bfr[j], acc[i][j], 0, 0, 0);
    __syncthreads();
  }

  const float* b1e = b1 + (size_t)e * ID;
#pragma unroll
  for (int j = 0; j < 4; j++) {
    int col = n0 + wn + j * 16 + lr;
    float bias = b1e[col];
#pragma unroll
    for (int i = 0; i < 4; i++) {
#pragma unroll
      for (int r = 0; r < 4; r++) {
        int mrow = wm + i * 16 + quad * 4 + r;
        int p = plist[mrow];
        if (p >= 0) {
          float v = acc[i][j][r] + bias;
          float g = 0.5f * v * (1.0f + erff(v * 0.70710678118654752f));  // exact-erf gelu
          hbuf[(size_t)p * ID + col] = __float2bfloat16(g);
        }
      }
    }
  }
}

// ---------------- grouped GEMM 2: pout = (h @ W2e + b2e) * gate_w ----------------
__global__ __launch_bounds__(256) void ffn2_kernel(
    const bf16* __restrict__ hbuf, const bf16* __restrict__ w2t, const float* __restrict__ b2,
    const int* __restrict__ counts, const int* __restrict__ elist,
    const float* __restrict__ pair_w, float* __restrict__ pout)
{
  __shared__ bf16 As[TM][LDA];
  __shared__ bf16 Bs[TN][LDA];
  __shared__ int plist[TM];

  int tid = threadIdx.x;
  int e, base = 0, cnt = 0, acct = 0;
  bool found = false;
  for (e = 0; e < NE; e++) {
    cnt = counts[e];
    int tiles = (cnt + TM - 1) / TM;
    if ((int)blockIdx.x < acct + tiles) { base = ((int)blockIdx.x - acct) * TM; found = true; break; }
    acct += tiles;
  }
  if (!found) return;

  if (tid < TM) {
    int r = base + tid;
    plist[tid] = (r < cnt) ? elist[e * NP + r] : -1;
  }
  __syncthreads();

  const int n0 = blockIdx.y * TN;
  const bf16* Bsrc = w2t + (size_t)e * HD * ID;  // [HD][ID] bf16, K-contiguous

  int wave = tid >> 6, lane = tid & 63;
  int wm = (wave & 1) << 6, wn = (wave >> 1) << 6;
  int lr = lane & 15, quad = lane >> 4;

  f32x4 acc[4][4] = {};

  for (int k0 = 0; k0 < ID; k0 += BK) {
#pragma unroll
    for (int c = tid; c < 512; c += 256) {
      int row = c >> 2, co = (c & 3) << 3;
      int p = plist[row];
      short8 v = {};
      if (p >= 0) v = *(const short8*)(hbuf + (size_t)p * ID + k0 + co);
      *(short8*)&As[row][co] = v;
    }
#pragma unroll
    for (int c = tid; c < 512; c += 256) {
      int row = c >> 2, co = (c & 3) << 3;
      *(short8*)&Bs[row][co] = *(const short8*)(Bsrc + (size_t)(n0 + row) * ID + k0 + co);
    }
    __syncthreads();
    short8 af[4], bfr[4];
#pragma unroll
    for (int i = 0; i < 4; i++) af[i] = *(const short8*)&As[wm + i * 16 + lr][quad * 8];
#pragma unroll
    for (int j = 0; j < 4; j++) bfr[j] = *(const short8*)&Bs[wn + j * 16 + lr][quad * 8];
#pragma unroll
    for (int i = 0; i < 4; i++)
#pragma unroll
      for (int j = 0; j < 4; j++)
        acc[i][j] = __builtin_amdgcn_mfma_f32_16x16x32_bf16(af[i], bfr[j], acc[i][j], 0, 0, 0);
    __syncthreads();
  }

  const float* b2e = b2 + (size_t)e * HD;
#pragma unroll
  for (int j = 0; j < 4; j++) {
    int col = n0 + wn + j * 16 + lr;
    float bias = b2e[col];
#pragma unroll
    for (int i = 0; i < 4; i++) {
#pragma unroll
      for (int r = 0; r < 4; r++) {
        int mrow = wm + i * 16 + quad * 4 + r;
        int p = plist[mrow];
        if (p >= 0) {
          float v = (acc[i][j][r] + bias) * pair_w[p];
          pout[(size_t)p * HD + col] = v;
        }
      }
    }
  }
}

// ---------------- combine the two expert contributions per token ----------------
__global__ __launch_bounds__(192) void combine_kernel(
    const float* __restrict__ pout, float* __restrict__ out)
{
  int t = blockIdx.x, j = threadIdx.x;  // 192 threads = 768/4
  const f32x4* a = (const f32x4*)(pout + (size_t)(2 * t) * HD);
  const f32x4* b = (const f32x4*)(pout + (size_t)(2 * t + 1) * HD);
  f32x4 o = a[j] + b[j];
  ((f32x4*)(out + (size_t)t * HD))[j] = o;
}

extern "C" void kernel_launch(void* const* d_in, const int* in_sizes, int n_in,
                              void* d_out, int out_size, void* d_ws, size_t ws_size,
                              hipStream_t stream)
{
  const float* x  = (const float*)d_in[0];
  const float* wg = (const float*)d_in[1];
  const float* bg = (const float*)d_in[2];
  const float* w1 = (const float*)d_in[3];
  const float* b1 = (const float*)d_in[4];
  const float* w2 = (const float*)d_in[5];
  const float* b2 = (const float*)d_in[6];
  float* out = (float*)d_out;
  float* gate_out = out + (size_t)NT * HD;  // second output [B,S,E]

  // workspace layout (~150 MB total)
  char* ws = (char*)d_ws;
  size_t off = 0;
  int* counts  = (int*)(ws + off);  off += 256;
  int* elist   = (int*)(ws + off);  off += (size_t)NE * NP * 4;
  float* pair_w = (float*)(ws + off); off += (size_t)NP * 4;
  bf16* xb   = (bf16*)(ws + off);   off += (size_t)NT * HD * 2;
  bf16* w1t  = (bf16*)(ws + off);   off += (size_t)NE * HD * ID * 2;
  bf16* w2t  = (bf16*)(ws + off);   off += (size_t)NE * HD * ID * 2;
  bf16* hbuf = (bf16*)(ws + off);   off += (size_t)NP * ID * 2;
  float* pout = (float*)(ws + off); off += (size_t)NP * HD * 4;

  hipMemsetAsync(counts, 0, 256, stream);
  gate_kernel<<<NT, 64, 0, stream>>>(x, wg, bg, gate_out, xb, pair_w, elist, counts);
  transpose_cvt_kernel<<<dim3(ID / 32, HD / 32, NE), 256, 0, stream>>>(w1, w1t, HD, ID);
  transpose_cvt_kernel<<<dim3(HD / 32, ID / 32, NE), 256, 0, stream>>>(w2, w2t, ID, HD);
  // max M-tiles = sum_e ceil(cnt_e/128) <= 70; 71 with early-exit keeps grid static
  ffn1_kernel<<<dim3(71, ID / TN), 256, 0, stream>>>(xb, w1t, b1, counts, elist, hbuf);
  ffn2_kernel<<<dim3(71, HD / TN), 256, 0, stream>>>(hbuf, w2t, b2, counts, elist, pair_w, pout);
  combine_kernel<<<NT, 192, 0, stream>>>(pout, out);
}